// Round 3
// baseline (285.252 us; speedup 1.0000x reference)
//
#include <hip/hip_runtime.h>
#include <stdint.h>

#define BATCH 2048
#define SIZE 4096
#define DOWN 256
#define NTASK 16
#define KC 16
#define KCHUNK (SIZE / KC)   // 256
#define XPAD 128             // slack rows past BATCH (reads of garbage are guarded at write)
#define ACTT_N (BATCH + XPAD)

typedef _Float16 half8 __attribute__((ext_vector_type(8)));
typedef float floatx4 __attribute__((ext_vector_type(4)));

// async global->LDS, 16B per lane. lds must be wave-uniform; data lands at lds + lane*16.
__device__ __forceinline__ void async_cp16(void* lds, const void* g) {
    __builtin_amdgcn_global_load_lds((const __attribute__((address_space(1))) uint32_t*)g,
                                     (__attribute__((address_space(3))) uint32_t*)lds, 16, 0, 0);
}

// ---------------- counting sort: group samples by task ----------------
__global__ __launch_bounds__(256) void sort_kernel(const int* __restrict__ task_id,
                                                   int* __restrict__ taskOff,
                                                   int* __restrict__ sortedIdx,
                                                   int* __restrict__ taskOfPos) {
    __shared__ int cnt[NTASK];
    __shared__ int base[NTASK + 1];
    __shared__ int cur[NTASK];
    int tid = threadIdx.x;
    if (tid < NTASK) cnt[tid] = 0;
    __syncthreads();
    for (int i = tid; i < BATCH; i += 256) atomicAdd(&cnt[task_id[i]], 1);
    __syncthreads();
    if (tid == 0) {
        int s = 0;
        for (int t = 0; t < NTASK; t++) { base[t] = s; s += cnt[t]; }
        base[NTASK] = s;
    }
    __syncthreads();
    if (tid < NTASK) { cur[tid] = base[tid]; taskOff[tid] = base[tid]; }
    if (tid == 0) taskOff[NTASK] = BATCH;
    __syncthreads();
    for (int i = tid; i < BATCH; i += 256) {
        int t = task_id[i];
        int p = atomicAdd(&cur[t], 1);
        sortedIdx[p] = i;
        taskOfPos[p] = t;
    }
}

// ---------------- convert+gather x -> fp16 sorted rows ----------------
__global__ __launch_bounds__(256) void cvt_x_kernel(const float* __restrict__ x,
                                                    const int* __restrict__ sortedIdx,
                                                    _Float16* __restrict__ x16) {
    int idx = blockIdx.x * 256 + threadIdx.x;  // BATCH * 512
    int pos = idx >> 9, col = (idx & 511) * 8;
    const float* src = x + (size_t)sortedIdx[pos] * SIZE + col;
    float4 f0 = *(const float4*)src;
    float4 f1 = *(const float4*)(src + 4);
    half8 h;
    h[0] = (_Float16)f0.x; h[1] = (_Float16)f0.y; h[2] = (_Float16)f0.z; h[3] = (_Float16)f0.w;
    h[4] = (_Float16)f1.x; h[5] = (_Float16)f1.y; h[6] = (_Float16)f1.z; h[7] = (_Float16)f1.w;
    *(half8*)(x16 + (size_t)pos * SIZE + col) = h;
}

// ---------------- convert Wd,Wu -> fp16 k-pack-8 [kg][n] layouts ----------------
// Wd16[(t*512+kg)*256 + n] = half8 of Wd[t][kg*8..+7][n]   (kg over K=4096)
// Wu16[(t*32 +kg)*4096+ n] = half8 of Wu[t][kg*8..+7][n]   (kg over K=256)
__global__ __launch_bounds__(256) void cvt_w_kernel(const float* __restrict__ Wd,
                                                    const float* __restrict__ Wu,
                                                    half8* __restrict__ Wd16,
                                                    half8* __restrict__ Wu16) {
    int b = blockIdx.x, tid = threadIdx.x;
    if (b < 8192) {
        int idx = b * 256 + tid;  // 16*512*256
        int n = idx & 255, kg = (idx >> 8) & 511, t = idx >> 17;
        const float* s = Wd + ((size_t)t * SIZE + kg * 8) * DOWN + n;
        half8 h;
#pragma unroll
        for (int e = 0; e < 8; e++) h[e] = (_Float16)s[(size_t)e * DOWN];
        Wd16[idx] = h;
    } else {
        int idx = (b - 8192) * 256 + tid;  // 16*32*4096
        int n = idx & 4095, kg = (idx >> 12) & 31, t = idx >> 17;
        const float* s = Wu + ((size_t)t * DOWN + kg * 8) * SIZE + n;
        half8 h;
#pragma unroll
        for (int e = 0; e < 8; e++) h[e] = (_Float16)s[(size_t)e * SIZE];
        Wu16[idx] = h;
    }
}

// ---------------- GEMM1: partial[kc][pos][h] = x16 @ Wd16 (K-chunked) ----------------
// 256 thr (4 waves 2m x 2n), tile M=128 x N=128, BK=64, 4 phases per block
__global__ __launch_bounds__(256, 4) void gemm1_kernel(const _Float16* __restrict__ x16,
                                                       const half8* __restrict__ Wd16,
                                                       const int* __restrict__ taskOff,
                                                       _Float16* __restrict__ partial) {
    int task = blockIdx.x, kc = blockIdx.y, nt = blockIdx.z;  // nt: 0..1
    int rowStart = taskOff[task];
    int nrows = taskOff[task + 1] - rowStart;
    if (nrows <= 0) return;

    __shared__ half8 A_lds[8][128];
    __shared__ half8 B_lds[8][128];

    int tid = threadIdx.x;
    int wave = tid >> 6, lane = tid & 63, quad = lane >> 4, l15 = lane & 15;
    int wm = wave >> 1, wn = wave & 1;
    int rowA = tid >> 1, j2 = tid & 1;

    for (int r0 = 0; r0 < nrows; r0 += 128) {
        floatx4 acc[4][4];
#pragma unroll
        for (int mi = 0; mi < 4; mi++)
#pragma unroll
            for (int ni = 0; ni < 4; ni++) acc[mi][ni] = (floatx4){0.f, 0.f, 0.f, 0.f};

        const _Float16* arow = x16 + (size_t)(rowStart + r0 + rowA) * SIZE;

#pragma unroll
        for (int ph = 0; ph < 4; ph++) {
            int k0 = kc * KCHUNK + ph * 64;
            __syncthreads();
            // ---- A: vectorized round-trip (rows are 8KB apart in x16)
            {
                const _Float16* s = arow + k0 + j2 * 32;
                half8 h0 = *(const half8*)(s);
                half8 h1 = *(const half8*)(s + 8);
                half8 h2 = *(const half8*)(s + 16);
                half8 h3 = *(const half8*)(s + 24);
                A_lds[j2 * 4 + 0][rowA] = h0;
                A_lds[j2 * 4 + 1][rowA] = h1;
                A_lds[j2 * 4 + 2][rowA] = h2;
                A_lds[j2 * 4 + 3][rowA] = h3;
            }
            // ---- B: async direct-to-LDS (lane-contiguous in Wd16)
            {
                int kgbase = task * 512 + (k0 >> 3);
#pragma unroll
                for (int jj = 0; jj < 2; jj++) {
                    int j = wave * 2 + jj;
#pragma unroll
                    for (int c = 0; c < 2; c++)
                        async_cp16(&B_lds[j][c * 64],
                                   Wd16 + (size_t)(kgbase + j) * 256 + nt * 128 + c * 64 + lane);
                }
            }
            __syncthreads();
#pragma unroll
            for (int ks = 0; ks < 2; ks++) {
                int kg = ks * 4 + quad;
                half8 a[4], b[4];
#pragma unroll
                for (int i = 0; i < 4; i++) a[i] = A_lds[kg][wm * 64 + i * 16 + l15];
#pragma unroll
                for (int i = 0; i < 4; i++) b[i] = B_lds[kg][wn * 64 + i * 16 + l15];
#pragma unroll
                for (int mi = 0; mi < 4; mi++)
#pragma unroll
                    for (int ni = 0; ni < 4; ni++)
                        acc[mi][ni] = __builtin_amdgcn_mfma_f32_16x16x32_f16(
                            a[mi], b[ni], acc[mi][ni], 0, 0, 0);
            }
        }
        // ---- epilogue: partial[kc][rowStart+r][h] fp16
#pragma unroll
        for (int mi = 0; mi < 4; mi++) {
#pragma unroll
            for (int reg = 0; reg < 4; reg++) {
                int r = r0 + wm * 64 + mi * 16 + quad * 4 + reg;
                if (r < nrows) {
                    size_t off = ((size_t)kc * BATCH + (rowStart + r)) * DOWN + nt * 128;
#pragma unroll
                    for (int ni = 0; ni < 4; ni++)
                        partial[off + wn * 64 + ni * 16 + l15] = (_Float16)acc[mi][ni][reg];
                }
            }
        }
    }
}

// ---------------- SiLU: actT[hg][pos] = silu(sum_kc partial + bd), k-pack-8 ----------------
__global__ __launch_bounds__(256) void silu_kernel(const half8* __restrict__ partial8,
                                                   const float* __restrict__ bd,
                                                   const int* __restrict__ taskOfPos,
                                                   half8* __restrict__ actT) {
    int idx = blockIdx.x * 256 + threadIdx.x;  // BATCH*32
    int s = idx >> 5, hg = idx & 31;
    const float* bdr = bd + taskOfPos[s] * DOWN + hg * 8;
    float v[8];
#pragma unroll
    for (int e = 0; e < 8; e++) v[e] = bdr[e];
#pragma unroll
    for (int kc = 0; kc < KC; kc++) {
        half8 p = partial8[((size_t)kc * BATCH + s) * 32 + hg];
#pragma unroll
        for (int e = 0; e < 8; e++) v[e] += (float)p[e];
    }
    half8 h;
#pragma unroll
    for (int e = 0; e < 8; e++) {
        float sv = v[e] / (1.0f + __expf(-v[e]));
        h[e] = (_Float16)sv;
    }
    actT[(size_t)hg * ACTT_N + s] = h;
}

// ---------------- GEMM2: out = x + actT @ Wu16 + bu ----------------
// 256 thr (4 waves 2m x 2n), tile M=128 x N=128, K=256, 4 phases; A and B both async
__global__ __launch_bounds__(256, 4) void gemm2_kernel(const half8* __restrict__ actT,
                                                       const half8* __restrict__ Wu16,
                                                       const float* __restrict__ bu,
                                                       const float* __restrict__ x,
                                                       const int* __restrict__ taskOff,
                                                       const int* __restrict__ sortedIdx,
                                                       float* __restrict__ out) {
    int task = blockIdx.x, nt = blockIdx.y;  // nt: 0..31
    int rowStart = taskOff[task];
    int nrows = taskOff[task + 1] - rowStart;
    if (nrows <= 0) return;

    __shared__ half8 A_lds[8][128];
    __shared__ half8 B_lds[8][128];

    int tid = threadIdx.x;
    int wave = tid >> 6, lane = tid & 63, quad = lane >> 4, l15 = lane & 15;
    int wm = wave >> 1, wn = wave & 1;
    int ncol0 = nt * 128;

    for (int r0 = 0; r0 < nrows; r0 += 128) {
        floatx4 acc[4][4];
#pragma unroll
        for (int mi = 0; mi < 4; mi++)
#pragma unroll
            for (int ni = 0; ni < 4; ni++) acc[mi][ni] = (floatx4){0.f, 0.f, 0.f, 0.f};

#pragma unroll
        for (int ph = 0; ph < 4; ph++) {
            int kgbase = ph * 8;
            __syncthreads();
#pragma unroll
            for (int jj = 0; jj < 2; jj++) {
                int j = wave * 2 + jj;
#pragma unroll
                for (int c = 0; c < 2; c++) {
                    async_cp16(&A_lds[j][c * 64],
                               actT + (size_t)(kgbase + j) * ACTT_N + rowStart + r0 + c * 64 + lane);
                    async_cp16(&B_lds[j][c * 64],
                               Wu16 + (size_t)(task * 32 + kgbase + j) * SIZE + ncol0 + c * 64 + lane);
                }
            }
            __syncthreads();
#pragma unroll
            for (int ks = 0; ks < 2; ks++) {
                int kg = ks * 4 + quad;
                half8 a[4], b[4];
#pragma unroll
                for (int i = 0; i < 4; i++) a[i] = A_lds[kg][wm * 64 + i * 16 + l15];
#pragma unroll
                for (int i = 0; i < 4; i++) b[i] = B_lds[kg][wn * 64 + i * 16 + l15];
#pragma unroll
                for (int mi = 0; mi < 4; mi++)
#pragma unroll
                    for (int ni = 0; ni < 4; ni++)
                        acc[mi][ni] = __builtin_amdgcn_mfma_f32_16x16x32_f16(
                            a[mi], b[ni], acc[mi][ni], 0, 0, 0);
            }
        }
        // ---- epilogue: scatter to original rows, add bias + fp32 residual
#pragma unroll
        for (int mi = 0; mi < 4; mi++) {
#pragma unroll
            for (int reg = 0; reg < 4; reg++) {
                int r = r0 + wm * 64 + mi * 16 + quad * 4 + reg;
                if (r < nrows) {
                    int b = sortedIdx[rowStart + r];
                    const float* xr = x + (size_t)b * SIZE;
                    float* outr = out + (size_t)b * SIZE;
#pragma unroll
                    for (int ni = 0; ni < 4; ni++) {
                        int n = ncol0 + wn * 64 + ni * 16 + l15;
                        outr[n] = acc[mi][ni][reg] + bu[task * SIZE + n] + xr[n];
                    }
                }
            }
        }
    }
}

extern "C" void kernel_launch(void* const* d_in, const int* in_sizes, int n_in,
                              void* d_out, int out_size, void* d_ws, size_t ws_size,
                              hipStream_t stream) {
    const float* x       = (const float*)d_in[0];
    const int*   task_id = (const int*)d_in[1];
    const float* Wd      = (const float*)d_in[2];
    const float* bd      = (const float*)d_in[3];
    const float* Wu      = (const float*)d_in[4];
    const float* bu      = (const float*)d_in[5];
    float* out = (float*)d_out;

    // d_out doubles as partial (16 MB of its 32 MB): dead before gemm2, which
    // overwrites every byte of d_out.
    _Float16* partial = (_Float16*)d_out;

    char* ws = (char*)d_ws;
    _Float16* x16 = (_Float16*)ws;            ws += (size_t)(BATCH + XPAD) * SIZE * 2;  // ~17 MB
    half8* Wd16   = (half8*)ws;               ws += (size_t)NTASK * 512 * 256 * 16;     // 32 MB
    half8* Wu16   = (half8*)ws;               ws += (size_t)NTASK * 32 * 4096 * 16;     // 32 MB
    half8* actT   = (half8*)ws;               ws += (size_t)32 * ACTT_N * 16;           // ~1 MB
    int* taskOff   = (int*)ws;
    int* sortedIdx = taskOff + 32;
    int* taskOfPos = sortedIdx + BATCH;

    sort_kernel<<<1, 256, 0, stream>>>(task_id, taskOff, sortedIdx, taskOfPos);
    cvt_x_kernel<<<(BATCH * 512) / 256, 256, 0, stream>>>(x, sortedIdx, x16);
    cvt_w_kernel<<<16384, 256, 0, stream>>>(Wd, Wu, Wd16, Wu16);
    gemm1_kernel<<<dim3(NTASK, KC, 2), 256, 0, stream>>>(x16, Wd16, taskOff, partial);
    silu_kernel<<<(BATCH * 32) / 256, 256, 0, stream>>>((const half8*)partial, bd, taskOfPos, actT);
    gemm2_kernel<<<dim3(NTASK, SIZE / 128), 256, 0, stream>>>(actT, Wu16, bu, x, taskOff,
                                                              sortedIdx, out);
}